// Round 4
// baseline (739.671 us; speedup 1.0000x reference)
//
#include <hip/hip_runtime.h>

typedef __attribute__((ext_vector_type(8))) short bf16x8;
typedef __attribute__((ext_vector_type(4))) float f32x4;

#define LOG2E 1.4426950408889634f

// CSR binning parameters: bins of 256 dst nodes
#define BINSH 8
#define NBIN 196        // ceil(50000/256)
#define CHUNK 4096      // edges per bin_scatter block
#define K4CAP 6144      // staged edges per bin in csr_build (avg 4096)
#define RPC 8           // rows per dynamic work chunk in conv kernels

__device__ __forceinline__ unsigned bf_rn(float f) {
    unsigned u = __float_as_uint(f);
    u += 0x7fffu + ((u >> 16) & 1u);
    return u >> 16;
}
__device__ __forceinline__ float bf_lo(unsigned u) { return __uint_as_float(u << 16); }
__device__ __forceinline__ float bf_hi(unsigned u) { return __uint_as_float(u & 0xffff0000u); }

// DPP add helpers (VALU pipe, no DS)
template <int CTRL>
__device__ __forceinline__ float dpp_radd(float x) {
    int t = __builtin_amdgcn_update_dpp(0, __float_as_int(x), CTRL, 0xF, 0xF, true);
    return x + __int_as_float(t);
}
// sum across aligned 8-lane group (all 8 lanes get the sum)
__device__ __forceinline__ float sum8(float p) {
    p = dpp_radd<0x141>(p);
    p = dpp_radd<0x1B>(p);
    p = dpp_radd<0xB1>(p);
    return p;
}
// sum across aligned 4-lane group (quad): swap-in-pair, then swap pairs
__device__ __forceinline__ float sum4(float p) {
    p = dpp_radd<0xB1>(p);   // quad_perm [1,0,3,2]
    p = dpp_radd<0x4E>(p);   // quad_perm [2,3,0,1]
    return p;
}
// neighbor swap (lane ^ 1) via quad_perm [1,0,3,2]
__device__ __forceinline__ float dpp_swap1(float x) {
    return __int_as_float(__builtin_amdgcn_update_dpp(0, __float_as_int(x), 0xB1, 0xF, 0xF, true));
}

__device__ __forceinline__ float fast_exp2(float x) {
#if __has_builtin(__builtin_amdgcn_exp2f)
    return __builtin_amdgcn_exp2f(x);
#else
    return __expf(x * 0.6931471805599453f);
#endif
}

// ---------------------------------------------------------------------------
// Binned CSR build (2-pass radix on dst)
// ---------------------------------------------------------------------------

__global__ __launch_bounds__(256) void bin_count(const int* __restrict__ dst,
                                                 int* __restrict__ binCnt, int e) {
    __shared__ int hist[NBIN];
    for (int t = threadIdx.x; t < NBIN; t += 256) hist[t] = 0;
    __syncthreads();
    int base = blockIdx.x * CHUNK;
    int cnt = min(CHUNK, e - base);
    for (int j = threadIdx.x; j < cnt; j += 256)
        atomicAdd(&hist[dst[base + j] >> BINSH], 1);
    __syncthreads();
    for (int t = threadIdx.x; t < NBIN; t += 256)
        if (hist[t]) atomicAdd(&binCnt[t], hist[t]);
}

__global__ void bin_scan(const int* __restrict__ binCnt, int* __restrict__ binBase,
                         int* __restrict__ binCur, int* __restrict__ rowp, int n, int e) {
    int t = threadIdx.x;
    int v = (t < NBIN) ? binCnt[t] : 0;
    int lane = t & 63, w = t >> 6;
    int incl = v;
    for (int off = 1; off < 64; off <<= 1) {
        int tt = __shfl_up(incl, off);
        if (lane >= off) incl += tt;
    }
    __shared__ int wsum[4];
    if (lane == 63) wsum[w] = incl;
    __syncthreads();
    int wpre = 0;
    for (int i = 0; i < w; ++i) wpre += wsum[i];
    int excl = wpre + incl - v;
    if (t < NBIN) { binBase[t] = excl; binCur[t] = excl; }
    if (t == 0) { binBase[NBIN] = e; rowp[n] = e; }
}

// Two-pass scatter: pass1 counts (LDS), parallel scan, pass2 re-reads src/dst
// (L2-hot) and packs via LDS cursor.
__global__ __launch_bounds__(256) void bin_scatter(
    const int* __restrict__ src, const int* __restrict__ dst,
    int* __restrict__ binCur, unsigned* __restrict__ ebin, int e) {
    __shared__ int hist[256];
    __shared__ int seg[256];
    __shared__ int gbase[NBIN];
    __shared__ unsigned pack[CHUNK];
    for (int t = threadIdx.x; t < 256; t += 256) hist[t] = 0;
    __syncthreads();
    int base = blockIdx.x * CHUNK;
    int cnt = min(CHUNK, e - base);

    // pass 1: count per bin
    for (int j = threadIdx.x; j < cnt; j += 256)
        atomicAdd(&hist[dst[base + j] >> BINSH], 1);
    __syncthreads();
    // parallel exclusive scan of 256 buckets with one wave (4 buckets/lane)
    if (threadIdx.x < 64) {
        int l = threadIdx.x;
        int s = 0, loc[4];
#pragma unroll
        for (int k = 0; k < 4; ++k) { loc[k] = s; s += hist[l * 4 + k]; }
        int incl = s;
        for (int off = 1; off < 64; off <<= 1) {
            int tt = __shfl_up(incl, off);
            if (l >= off) incl += tt;
        }
        int excl = incl - s;
#pragma unroll
        for (int k = 0; k < 4; ++k) seg[l * 4 + k] = excl + loc[k];
    }
    __syncthreads();
    // grab global base per non-empty bin, then convert hist -> local cursor
    if (threadIdx.x < NBIN && hist[threadIdx.x])
        gbase[threadIdx.x] = atomicAdd(&binCur[threadIdx.x], hist[threadIdx.x]);
    __syncthreads();
    for (int t = threadIdx.x; t < 256; t += 256) hist[t] = seg[t];
    __syncthreads();
    // pass 2: re-read (L2 hit) and pack into bin-sorted LDS
    for (int j = threadIdx.x; j < cnt; j += 256) {
        int d = dst[base + j], s = src[base + j];
        int b = d >> BINSH, dl = d & ((1 << BINSH) - 1);
        int pos = atomicAdd(&hist[b], 1);
        pack[pos] = ((unsigned)b << 24) | ((unsigned)dl << 16) | (unsigned)s;
    }
    __syncthreads();
    // coalesced-ish global write per bin run
    for (int j = threadIdx.x; j < cnt; j += 256) {
        unsigned wv = pack[j];
        int b = wv >> 24;
        ebin[gbase[b] + (j - seg[b])] = wv;
    }
}

__global__ __launch_bounds__(256) void csr_build(
    const unsigned* __restrict__ ebin, const int* __restrict__ binBase,
    int* __restrict__ rowp, int* __restrict__ csrc, int n) {
    __shared__ int hist[256];
    __shared__ int seg[256];
    __shared__ unsigned stage[K4CAP];
    int b = blockIdx.x;
    int e0 = binBase[b], e1 = binBase[b + 1];
    int n0 = b << BINSH;
    int nn = min(256, n - n0);
    for (int t = threadIdx.x; t < 256; t += 256) hist[t] = 0;
    __syncthreads();
    for (int i = e0 + threadIdx.x; i < e1; i += 256) {
        unsigned wv = ebin[i];
        atomicAdd(&hist[(wv >> 16) & 255], 1);
        int off = i - e0;
        if (off < K4CAP) stage[off] = wv;
    }
    __syncthreads();
    if (threadIdx.x < 64) {
        int l = threadIdx.x;
        int s = 0, loc[4];
#pragma unroll
        for (int k = 0; k < 4; ++k) { loc[k] = s; s += hist[l * 4 + k]; }
        int incl = s;
        for (int off = 1; off < 64; off <<= 1) {
            int tt = __shfl_up(incl, off);
            if (l >= off) incl += tt;
        }
        int excl = incl - s;
#pragma unroll
        for (int k = 0; k < 4; ++k) seg[l * 4 + k] = excl + loc[k];
    }
    __syncthreads();
    for (int t = threadIdx.x; t < nn; t += 256) rowp[n0 + t] = e0 + seg[t];
    for (int t = threadIdx.x; t < 256; t += 256) hist[t] = seg[t];
    __syncthreads();
    for (int i = e0 + threadIdx.x; i < e1; i += 256) {
        int off = i - e0;
        unsigned wv = (off < K4CAP) ? stage[off] : ebin[i];
        int dl = (wv >> 16) & 255;
        int pos = e0 + atomicAdd(&hist[dl], 1);
        csrc[pos] = (int)(wv & 0xFFFFu);
    }
}

// ---------------------------------------------------------------------------
// Merged prep: feature fp32->bf16, weight transpose+convert, counter zeroing
// ---------------------------------------------------------------------------

__global__ __launch_bounds__(256) void prep(
    const float* __restrict__ x, unsigned short* __restrict__ xb, int n4,
    const float* __restrict__ Ws0, const float* __restrict__ Wd0,
    const float* __restrict__ Ws1, const float* __restrict__ Wd1,
    const float* __restrict__ Ws2, const float* __restrict__ Wd2,
    unsigned short* __restrict__ wt0, unsigned short* __restrict__ wt1,
    unsigned short* __restrict__ wt2, int* __restrict__ binCnt,
    int* __restrict__ wkctr) {
    int gid = blockIdx.x * blockDim.x + threadIdx.x;
    if (gid < NBIN) binCnt[gid] = 0;   // replaces hipMemsetAsync dispatch
    if (gid < 8) wkctr[gid] = 0;       // conv work-chunk counters
    if (gid < n4) {
        float4 v = *(const float4*)(x + (size_t)gid * 4);
        ushort4 r;
        r.x = (unsigned short)bf_rn(v.x); r.y = (unsigned short)bf_rn(v.y);
        r.z = (unsigned short)bf_rn(v.z); r.w = (unsigned short)bf_rn(v.w);
        *(ushort4*)(xb + (size_t)gid * 4) = r;
    } else {
        int g = gid - n4;
        if (g < 65536) {
            int l = g >> 15, loc = g & 32767;
            int c = loc >> 7, k = loc & 127;
            const float* W = (c < 128) ? (l ? Ws1 : Ws0) : (l ? Wd1 : Wd0);
            int cc = c & 127;
            float v = W[(size_t)k * 128 + cc];
            (l ? wt1 : wt0)[loc] = (unsigned short)bf_rn(v);
        } else if (g < 65536 + 8192) {
            int loc = g - 65536;
            int c = loc >> 7, k = loc & 127;
            const float* W = (c < 32) ? Ws2 : Wd2;
            int cc = (c < 32) ? c : c - 32;
            float v = W[(size_t)k * 32 + cc];
            wt2[loc] = (unsigned short)bf_rn(v);
        }
    }
}

// ---------------------------------------------------------------------------
// Zero-LDS MFMA dual GEMM: [fs|fd] = x @ [Ws|Wd] + [bs|bd].
// ---------------------------------------------------------------------------

template <int COLS2>
__global__ __launch_bounds__(256) void gemm_dual2(
    const unsigned short* __restrict__ xb, const unsigned short* __restrict__ wt,
    const float* __restrict__ bs, const float* __restrict__ bd,
    unsigned short* __restrict__ fs, unsigned short* __restrict__ fd,
    int n, int nch) {
    constexpr int C  = COLS2 / 2;
    constexpr int NC = COLS2 / 64;

    const int lane = threadIdx.x & 63;
    const int m = lane & 15, quad = lane >> 4;
    const int gwid = blockIdx.x * 4 + (threadIdx.x >> 6);
    const int nwaves = gridDim.x * 4;
    const int cs = gwid % NC;
    const int cstride = nwaves / NC;

    float biasv[4];
#pragma unroll
    for (int ct = 0; ct < 4; ++ct) {
        int col = cs * 64 + ct * 16 + m;
        biasv[ct] = (col < C) ? bs[col] : bd[col - C];
    }

    for (int chunk = gwid / NC; chunk < nch; chunk += cstride) {
        const size_t r0 = (size_t)chunk * 64;

        f32x4 acc[4][4];
#pragma unroll
        for (int rt = 0; rt < 4; ++rt)
#pragma unroll
            for (int ct = 0; ct < 4; ++ct) acc[rt][ct] = (f32x4){0.f, 0.f, 0.f, 0.f};

#pragma unroll
        for (int ks = 0; ks < 4; ++ks) {
            const int ko = ks * 32 + quad * 8;
            bf16x8 a[4], b[4];
#pragma unroll
            for (int rt = 0; rt < 4; ++rt)
                a[rt] = *(const bf16x8*)(xb + (r0 + rt * 16 + m) * 128 + ko);
#pragma unroll
            for (int ct = 0; ct < 4; ++ct)
                b[ct] = *(const bf16x8*)(wt + (size_t)(cs * 64 + ct * 16 + m) * 128 + ko);
#pragma unroll
            for (int rt = 0; rt < 4; ++rt)
#pragma unroll
                for (int ct = 0; ct < 4; ++ct)
                    acc[rt][ct] = __builtin_amdgcn_mfma_f32_16x16x32_bf16(a[rt], b[ct], acc[rt][ct], 0, 0, 0);
        }

        const int odd = m & 1;
#pragma unroll
        for (int ct = 0; ct < 4; ++ct) {
            int colE = cs * 64 + ct * 16 + (m & ~1);
            unsigned short* ptr = (colE < C) ? fs : fd;
            int cc = (colE < C) ? colE : colE - C;
#pragma unroll
            for (int rt = 0; rt < 4; ++rt) {
                float v0 = acc[rt][ct][0] + biasv[ct];
                float v1 = acc[rt][ct][1] + biasv[ct];
                float v2 = acc[rt][ct][2] + biasv[ct];
                float v3 = acc[rt][ct][3] + biasv[ct];
                float s0 = dpp_swap1(v0), s1 = dpp_swap1(v1);
                float s2 = dpp_swap1(v2), s3 = dpp_swap1(v3);
                float aLo = odd ? s2 : v0, aHi = odd ? v2 : s0;
                float bLo = odd ? s3 : v1, bHi = odd ? v3 : s1;
                int rowA = (int)r0 + rt * 16 + quad * 4 + (odd ? 2 : 0);
                unsigned pa = (bf_rn(aHi) << 16) | bf_rn(aLo);
                unsigned pb = (bf_rn(bHi) << 16) | bf_rn(bLo);
                if (rowA < n)     *(unsigned*)(ptr + (size_t)rowA * C + cc)       = pa;
                if (rowA + 1 < n) *(unsigned*)(ptr + ((size_t)rowA + 1) * C + cc) = pb;
            }
        }
    }
}

// ---------------------------------------------------------------------------
// GATv2 aggregation.
// conv128: 4 edge slots/wave (16 lanes x 8 feats each); 16-edge bursts
//          (4 uint4 gathers in flight per wave). Dynamic 8-row work chunks.
// conv32:  8 edge slots/wave (8 lanes x 4 feats), 16-edge bursts.
// ---------------------------------------------------------------------------

// per-edge math for conv32: 4 feats/lane, 8-lane head groups
#define EDGE_BODY(u, mval)                                          \
    do {                                                            \
        float x0 = bf_lo((u).x), x1 = bf_hi((u).x);                 \
        float x2 = bf_lo((u).y), x3 = bf_hi((u).y);                 \
        float t0 = x0 + fd0, t1 = x1 + fd1;                         \
        float t2 = x2 + fd2, t3 = x3 + fd3;                         \
        float p = a060 * t0;                                        \
        p = fmaf(a040, fabsf(t0), p);                               \
        p = fmaf(a061, t1, p); p = fmaf(a041, fabsf(t1), p);        \
        p = fmaf(a062, t2, p); p = fmaf(a042, fabsf(t2), p);        \
        p = fmaf(a063, t3, p); p = fmaf(a043, fabsf(t3), p);        \
        p = sum8(p);                                                \
        float ex = fast_exp2(p) * (mval);                           \
        denom += ex;                                                \
        acc0 = fmaf(ex, x0, acc0); acc1 = fmaf(ex, x1, acc1);       \
        acc2 = fmaf(ex, x2, acc2); acc3 = fmaf(ex, x3, acc3);       \
    } while (0)

// per-edge math for conv128: 8 feats/lane, 4-lane head groups.
// Logit accumulated in two independent 8-deep FMA chains (p0, p1).
#define EB8(u, mval)                                                \
    do {                                                            \
        float x0 = bf_lo((u).x), x1 = bf_hi((u).x);                 \
        float x2 = bf_lo((u).y), x3 = bf_hi((u).y);                 \
        float x4 = bf_lo((u).z), x5 = bf_hi((u).z);                 \
        float x6 = bf_lo((u).w), x7 = bf_hi((u).w);                 \
        float t0 = x0 + fd0, t1 = x1 + fd1;                         \
        float t2 = x2 + fd2, t3 = x3 + fd3;                         \
        float t4 = x4 + fd4, t5 = x5 + fd5;                         \
        float t6 = x6 + fd6, t7 = x7 + fd7;                         \
        float p0 = a60_0 * t0;                                      \
        p0 = fmaf(a40_0, fabsf(t0), p0);                            \
        p0 = fmaf(a60_1, t1, p0); p0 = fmaf(a40_1, fabsf(t1), p0);  \
        p0 = fmaf(a60_2, t2, p0); p0 = fmaf(a40_2, fabsf(t2), p0);  \
        p0 = fmaf(a60_3, t3, p0); p0 = fmaf(a40_3, fabsf(t3), p0);  \
        float p1 = a60_4 * t4;                                      \
        p1 = fmaf(a40_4, fabsf(t4), p1);                            \
        p1 = fmaf(a60_5, t5, p1); p1 = fmaf(a40_5, fabsf(t5), p1);  \
        p1 = fmaf(a60_6, t6, p1); p1 = fmaf(a40_6, fabsf(t6), p1);  \
        p1 = fmaf(a60_7, t7, p1); p1 = fmaf(a40_7, fabsf(t7), p1);  \
        float p = sum4(p0 + p1);                                    \
        float ex = fast_exp2(p) * (mval);                           \
        denom += ex;                                                \
        acc0 = fmaf(ex, x0, acc0); acc1 = fmaf(ex, x1, acc1);       \
        acc2 = fmaf(ex, x2, acc2); acc3 = fmaf(ex, x3, acc3);       \
        acc4 = fmaf(ex, x4, acc4); acc5 = fmaf(ex, x5, acc5);       \
        acc6 = fmaf(ex, x6, acc6); acc7 = fmaf(ex, x7, acc7);       \
    } while (0)

__global__ __launch_bounds__(256) void conv128(
    const unsigned short* __restrict__ fs, const unsigned short* __restrict__ fd,
    const float* __restrict__ attn, const int* __restrict__ rowp,
    const int* __restrict__ csrc, unsigned short* __restrict__ out, int n,
    int* __restrict__ wkctr) {
    const int lane = threadIdx.x & 63;
    const int slot = lane >> 4;     // edge slot [0,4)
    const int c = lane & 15;        // 8-feat chunk [0,16); head = c>>2

    float4 av0 = *(const float4*)(attn + c * 8);
    float4 av1 = *(const float4*)(attn + c * 8 + 4);
    const float a60_0 = av0.x * 0.6f * LOG2E, a40_0 = av0.x * 0.4f * LOG2E;
    const float a60_1 = av0.y * 0.6f * LOG2E, a40_1 = av0.y * 0.4f * LOG2E;
    const float a60_2 = av0.z * 0.6f * LOG2E, a40_2 = av0.z * 0.4f * LOG2E;
    const float a60_3 = av0.w * 0.6f * LOG2E, a40_3 = av0.w * 0.4f * LOG2E;
    const float a60_4 = av1.x * 0.6f * LOG2E, a40_4 = av1.x * 0.4f * LOG2E;
    const float a60_5 = av1.y * 0.6f * LOG2E, a40_5 = av1.y * 0.4f * LOG2E;
    const float a60_6 = av1.z * 0.6f * LOG2E, a40_6 = av1.z * 0.4f * LOG2E;
    const float a60_7 = av1.w * 0.6f * LOG2E, a40_7 = av1.w * 0.4f * LOG2E;

    const unsigned short* fsc = fs + c * 8;  // per-lane feature base

    for (;;) {
        // wave grabs a chunk of RPC rows (dynamic load balance)
        int ch;
        if (lane == 0) ch = atomicAdd(wkctr, 1);
        ch = __shfl(ch, 0);
        const int row0 = ch * RPC;
        if (row0 >= n) break;
        const int rowE = min(row0 + RPC, n);

        for (int row = row0; row < rowE; ++row) {
            uint4 ud = *(const uint4*)(fd + (size_t)row * 128 + c * 8);
            float fd0 = bf_lo(ud.x), fd1 = bf_hi(ud.x);
            float fd2 = bf_lo(ud.y), fd3 = bf_hi(ud.y);
            float fd4 = bf_lo(ud.z), fd5 = bf_hi(ud.z);
            float fd6 = bf_lo(ud.w), fd7 = bf_hi(ud.w);
            int rs = rowp[row], re = rowp[row + 1];
            float acc0 = 0.f, acc1 = 0.f, acc2 = 0.f, acc3 = 0.f;
            float acc4 = 0.f, acc5 = 0.f, acc6 = 0.f, acc7 = 0.f, denom = 0.f;

            int i = rs;
            // 16-edge burst: 4 row-gathers in flight per wave
            for (; i + 15 < re; i += 16) {
                int s0 = csrc[i + slot];
                int s1 = csrc[i + 4 + slot];
                int s2 = csrc[i + 8 + slot];
                int s3 = csrc[i + 12 + slot];
                uint4 u0 = *(const uint4*)(fsc + ((size_t)s0 << 7));
                uint4 u1 = *(const uint4*)(fsc + ((size_t)s1 << 7));
                uint4 u2 = *(const uint4*)(fsc + ((size_t)s2 << 7));
                uint4 u3 = *(const uint4*)(fsc + ((size_t)s3 << 7));
                EB8(u0, 1.0f);
                EB8(u1, 1.0f);
                EB8(u2, 1.0f);
                EB8(u3, 1.0f);
            }
            for (; i + 7 < re; i += 8) {
                int s0 = csrc[i + slot];
                int s1 = csrc[i + 4 + slot];
                uint4 u0 = *(const uint4*)(fsc + ((size_t)s0 << 7));
                uint4 u1 = *(const uint4*)(fsc + ((size_t)s1 << 7));
                EB8(u0, 1.0f);
                EB8(u1, 1.0f);
            }
            for (; i + 3 < re; i += 4) {
                int s = csrc[i + slot];
                uint4 u = *(const uint4*)(fsc + ((size_t)s << 7));
                EB8(u, 1.0f);
            }
            if (i < re) {  // masked tail group (1-3 valid edges)
                int idx = i + slot;
                int s = csrc[min(idx, re - 1)];
                uint4 u = *(const uint4*)(fsc + ((size_t)s << 7));
                float mval = (idx < re) ? 1.f : 0.f;
                EB8(u, mval);
            }
            // combine the four edge slots
            acc0 += __shfl_xor(acc0, 16); acc1 += __shfl_xor(acc1, 16);
            acc2 += __shfl_xor(acc2, 16); acc3 += __shfl_xor(acc3, 16);
            acc4 += __shfl_xor(acc4, 16); acc5 += __shfl_xor(acc5, 16);
            acc6 += __shfl_xor(acc6, 16); acc7 += __shfl_xor(acc7, 16);
            denom += __shfl_xor(denom, 16);
            acc0 += __shfl_xor(acc0, 32); acc1 += __shfl_xor(acc1, 32);
            acc2 += __shfl_xor(acc2, 32); acc3 += __shfl_xor(acc3, 32);
            acc4 += __shfl_xor(acc4, 32); acc5 += __shfl_xor(acc5, 32);
            acc6 += __shfl_xor(acc6, 32); acc7 += __shfl_xor(acc7, 32);
            denom += __shfl_xor(denom, 32);
            float inv = (re > rs) ? 1.f / denom : 0.f;
            float r0 = fmaxf(acc0 * inv, 0.f), r1 = fmaxf(acc1 * inv, 0.f);
            float r2 = fmaxf(acc2 * inv, 0.f), r3 = fmaxf(acc3 * inv, 0.f);
            float r4 = fmaxf(acc4 * inv, 0.f), r5 = fmaxf(acc5 * inv, 0.f);
            float r6 = fmaxf(acc6 * inv, 0.f), r7 = fmaxf(acc7 * inv, 0.f);
            if (slot == 0) {
                uint4 o;
                o.x = (bf_rn(r1) << 16) | bf_rn(r0);
                o.y = (bf_rn(r3) << 16) | bf_rn(r2);
                o.z = (bf_rn(r5) << 16) | bf_rn(r4);
                o.w = (bf_rn(r7) << 16) | bf_rn(r6);
                *(uint4*)(out + (size_t)row * 128 + c * 8) = o;
            }
        }
    }
}

// Layer 2: 1 head x 32 feats; 8 edges/wave, 8 lanes (4 feats each) per edge.
__global__ __launch_bounds__(256) void conv32(
    const unsigned short* __restrict__ fs, const unsigned short* __restrict__ fd,
    const float* __restrict__ attn, const int* __restrict__ rowp,
    const int* __restrict__ csrc, float* __restrict__ out, int n,
    int* __restrict__ wkctr) {
    const int lane = threadIdx.x & 63;
    const int g = lane >> 3;    // edge slot [0,8)
    const int c = lane & 7;     // 4-feat chunk [0,8)

    float4 av = *(const float4*)(attn + c * 4);
    const float a060 = av.x * 0.6f * LOG2E, a040 = av.x * 0.4f * LOG2E;
    const float a061 = av.y * 0.6f * LOG2E, a041 = av.y * 0.4f * LOG2E;
    const float a062 = av.z * 0.6f * LOG2E, a042 = av.z * 0.4f * LOG2E;
    const float a063 = av.w * 0.6f * LOG2E, a043 = av.w * 0.4f * LOG2E;

    const unsigned short* fsc = fs + c * 4;

    for (;;) {
        int ch;
        if (lane == 0) ch = atomicAdd(wkctr, 1);
        ch = __shfl(ch, 0);
        const int row0 = ch * RPC;
        if (row0 >= n) break;
        const int rowE = min(row0 + RPC, n);

        for (int row = row0; row < rowE; ++row) {
            uint2 ud = *(const uint2*)(fd + (size_t)row * 32 + c * 4);
            float fd0 = bf_lo(ud.x), fd1 = bf_hi(ud.x);
            float fd2 = bf_lo(ud.y), fd3 = bf_hi(ud.y);
            int rs = rowp[row], re = rowp[row + 1];
            float acc0 = 0.f, acc1 = 0.f, acc2 = 0.f, acc3 = 0.f, denom = 0.f;

            int i = rs;
            // 16 edges (2 groups of 8) in flight
            for (; i + 15 < re; i += 16) {
                int s0 = csrc[i + g];
                int s1 = csrc[i + 8 + g];
                uint2 u0 = *(const uint2*)(fsc + ((size_t)s0 << 5));
                uint2 u1 = *(const uint2*)(fsc + ((size_t)s1 << 5));
                EDGE_BODY(u0, 1.0f);
                EDGE_BODY(u1, 1.0f);
            }
            for (; i + 7 < re; i += 8) {
                int s = csrc[i + g];
                uint2 u = *(const uint2*)(fsc + ((size_t)s << 5));
                EDGE_BODY(u, 1.0f);
            }
            if (i < re) {  // masked tail group
                int idx = i + g;
                int s = csrc[min(idx, re - 1)];
                uint2 u = *(const uint2*)(fsc + ((size_t)s << 5));
                float mval = (idx < re) ? 1.f : 0.f;
                EDGE_BODY(u, mval);
            }
            // combine the 8 edge slots: rot8-within-16 (DPP), then xor 16, 32
            acc0 = dpp_radd<0x128>(acc0); acc1 = dpp_radd<0x128>(acc1);
            acc2 = dpp_radd<0x128>(acc2); acc3 = dpp_radd<0x128>(acc3);
            denom = dpp_radd<0x128>(denom);
            acc0 += __shfl_xor(acc0, 16); acc1 += __shfl_xor(acc1, 16);
            acc2 += __shfl_xor(acc2, 16); acc3 += __shfl_xor(acc3, 16);
            denom += __shfl_xor(denom, 16);
            acc0 += __shfl_xor(acc0, 32); acc1 += __shfl_xor(acc1, 32);
            acc2 += __shfl_xor(acc2, 32); acc3 += __shfl_xor(acc3, 32);
            denom += __shfl_xor(denom, 32);
            float inv = (re > rs) ? 1.f / denom : 0.f;
            if (lane < 8) {
                float4 o;
                o.x = acc0 * inv; o.y = acc1 * inv;
                o.z = acc2 * inv; o.w = acc3 * inv;
                *(float4*)(out + (size_t)row * 32 + c * 4) = o;
            }
        }
    }
}

// ---------------------------------------------------------------------------

extern "C" void kernel_launch(void* const* d_in, const int* in_sizes, int n_in,
                              void* d_out, int out_size, void* d_ws, size_t ws_size,
                              hipStream_t stream) {
    const float* feats = (const float*)d_in[0];
    const int*   src   = (const int*)d_in[1];
    const int*   dst   = (const int*)d_in[2];
    const float* Ws0 = (const float*)d_in[3],  *bs0 = (const float*)d_in[4];
    const float* Wd0 = (const float*)d_in[5],  *bd0 = (const float*)d_in[6];
    const float* a0  = (const float*)d_in[7];
    const float* Ws1 = (const float*)d_in[8],  *bs1 = (const float*)d_in[9];
    const float* Wd1 = (const float*)d_in[10], *bd1 = (const float*)d_in[11];
    const float* a1  = (const float*)d_in[12];
    const float* Ws2 = (const float*)d_in[13], *bs2 = (const float*)d_in[14];
    const float* Wd2 = (const float*)d_in[15], *bd2 = (const float*)d_in[16];
    const float* a2  = (const float*)d_in[17];

    const int N = in_sizes[0] / 128;  // 50000
    const int E = in_sizes[1];        // 800000
    const int nch = (N + 63) / 64;
    const int NPAD = nch * 64;

    char* ws = (char*)d_ws;
    const size_t featB = (size_t)NPAD * 128 * 2;
    unsigned short* xb  = (unsigned short*)(ws);
    unsigned short* hb  = (unsigned short*)(ws + featB);
    unsigned short* fsb = (unsigned short*)(ws + 2 * featB);
    unsigned short* fdb = (unsigned short*)(ws + 3 * featB);
    char* p = ws + 4 * featB;
    unsigned short* wt0 = (unsigned short*)p; p += 256 * 128 * 2;
    unsigned short* wt1 = (unsigned short*)p; p += 256 * 128 * 2;
    unsigned short* wt2 = (unsigned short*)p; p += 64 * 128 * 2;
    int* rowp    = (int*)p;      p += ((size_t)(N + 1) * 4 + 255) / 256 * 256;
    int* binCnt  = (int*)p;      p += (NBIN * 4 + 255) / 256 * 256;
    int* binBase = (int*)p;      p += ((NBIN + 1) * 4 + 255) / 256 * 256;
    int* binCur  = (int*)p;      p += (NBIN * 4 + 255) / 256 * 256;
    int* wkctr   = (int*)p;      p += 256;
    unsigned* ebin = (unsigned*)p; p += (size_t)E * 4;
    int* csrc    = (int*)p;

    const int nchunks = (E + CHUNK - 1) / CHUNK;
    const int n4 = N * 128 / 4;

    // ---- prep (feat convert + weight transpose + counter zero) ----
    prep<<<(n4 + 73728 + 255) / 256, 256, 0, stream>>>(
        feats, xb, n4, Ws0, Wd0, Ws1, Wd1, Ws2, Wd2, wt0, wt1, wt2, binCnt, wkctr);

    // ---- binned CSR build ----
    bin_count<<<nchunks, 256, 0, stream>>>(dst, binCnt, E);
    bin_scan<<<1, 256, 0, stream>>>(binCnt, binBase, binCur, rowp, N, E);
    bin_scatter<<<nchunks, 256, 0, stream>>>(src, dst, binCur, ebin, E);
    csr_build<<<NBIN, 256, 0, stream>>>(ebin, binBase, rowp, csrc, N);

    const int g256 = nch;
    const int g64  = (nch + 3) / 4;
    const int convGrid = 2048;  // 8192 waves = full device capacity

    // ---- layer 0 ----
    gemm_dual2<256><<<g256, 256, 0, stream>>>(xb, wt0, bs0, bd0, fsb, fdb, N, nch);
    conv128<<<convGrid, 256, 0, stream>>>(fsb, fdb, a0, rowp, csrc, hb, N, &wkctr[0]);
    // ---- layer 1 ----
    gemm_dual2<256><<<g256, 256, 0, stream>>>(hb, wt1, bs1, bd1, fsb, fdb, N, nch);
    conv128<<<convGrid, 256, 0, stream>>>(fsb, fdb, a1, rowp, csrc, hb, N, &wkctr[1]);
    // ---- layer 2 ----
    gemm_dual2<64><<<g64, 256, 0, stream>>>(hb, wt2, bs2, bd2, fsb, fdb, N, nch);
    conv32<<<convGrid, 256, 0, stream>>>(fsb, fdb, a2, rowp, csrc, (float*)d_out, N, &wkctr[2]);
}

// Round 5
// 282.251 us; speedup vs baseline: 2.6206x; 2.6206x over previous
//
#include <hip/hip_runtime.h>

typedef __attribute__((ext_vector_type(8))) short bf16x8;
typedef __attribute__((ext_vector_type(4))) float f32x4;

#define LOG2E 1.4426950408889634f

// CSR binning parameters: bins of 256 dst nodes
#define BINSH 8
#define NBIN 196        // ceil(50000/256)
#define CHUNK 4096      // edges per bin_scatter block
#define K4CAP 6144      // staged edges per bin in csr_build (avg 4096)

__device__ __forceinline__ unsigned bf_rn(float f) {
    unsigned u = __float_as_uint(f);
    u += 0x7fffu + ((u >> 16) & 1u);
    return u >> 16;
}
__device__ __forceinline__ float bf_lo(unsigned u) { return __uint_as_float(u << 16); }
__device__ __forceinline__ float bf_hi(unsigned u) { return __uint_as_float(u & 0xffff0000u); }

// DPP add helpers (VALU pipe, no DS)
template <int CTRL>
__device__ __forceinline__ float dpp_radd(float x) {
    int t = __builtin_amdgcn_update_dpp(0, __float_as_int(x), CTRL, 0xF, 0xF, true);
    return x + __int_as_float(t);
}
// sum across aligned 8-lane group (all 8 lanes get the sum)
__device__ __forceinline__ float sum8(float p) {
    p = dpp_radd<0x141>(p);
    p = dpp_radd<0x1B>(p);
    p = dpp_radd<0xB1>(p);
    return p;
}
// neighbor swap (lane ^ 1) via quad_perm [1,0,3,2]
__device__ __forceinline__ float dpp_swap1(float x) {
    return __int_as_float(__builtin_amdgcn_update_dpp(0, __float_as_int(x), 0xB1, 0xF, 0xF, true));
}

__device__ __forceinline__ float fast_exp2(float x) {
#if __has_builtin(__builtin_amdgcn_exp2f)
    return __builtin_amdgcn_exp2f(x);
#else
    return __expf(x * 0.6931471805599453f);
#endif
}

// ---------------------------------------------------------------------------
// Merged prep: feature fp32->bf16, weight transpose+convert, counter zeroing
// ---------------------------------------------------------------------------

__global__ __launch_bounds__(256) void prep(
    const float* __restrict__ x, unsigned short* __restrict__ xb, int n4,
    const float* __restrict__ Ws0, const float* __restrict__ Wd0,
    const float* __restrict__ Ws1, const float* __restrict__ Wd1,
    const float* __restrict__ Ws2, const float* __restrict__ Wd2,
    unsigned short* __restrict__ wt0, unsigned short* __restrict__ wt1,
    unsigned short* __restrict__ wt2, int* __restrict__ binCnt,
    int* __restrict__ binOff) {
    int gid = blockIdx.x * blockDim.x + threadIdx.x;
    if (gid < NBIN) { binCnt[gid] = 0; binOff[gid] = 0; }
    if (gid < n4) {
        float4 v = *(const float4*)(x + (size_t)gid * 4);
        ushort4 r;
        r.x = (unsigned short)bf_rn(v.x); r.y = (unsigned short)bf_rn(v.y);
        r.z = (unsigned short)bf_rn(v.z); r.w = (unsigned short)bf_rn(v.w);
        *(ushort4*)(xb + (size_t)gid * 4) = r;
    } else {
        int g = gid - n4;
        if (g < 65536) {
            int l = g >> 15, loc = g & 32767;
            int c = loc >> 7, k = loc & 127;
            const float* W = (c < 128) ? (l ? Ws1 : Ws0) : (l ? Wd1 : Wd0);
            int cc = c & 127;
            float v = W[(size_t)k * 128 + cc];
            (l ? wt1 : wt0)[loc] = (unsigned short)bf_rn(v);
        } else if (g < 65536 + 8192) {
            int loc = g - 65536;
            int c = loc >> 7, k = loc & 127;
            const float* W = (c < 32) ? Ws2 : Wd2;
            int cc = (c < 32) ? c : c - 32;
            float v = W[(size_t)k * 32 + cc];
            wt2[loc] = (unsigned short)bf_rn(v);
        }
    }
}

// ---------------------------------------------------------------------------
// Zero-LDS MFMA dual GEMM core: [fs|fd] = x @ [Ws|Wd] + [bs|bd].
// ---------------------------------------------------------------------------

template <int COLS2>
__device__ __forceinline__ void gemm_core(
    const unsigned short* __restrict__ xb, const unsigned short* __restrict__ wt,
    const float* __restrict__ bs, const float* __restrict__ bd,
    unsigned short* __restrict__ fs, unsigned short* __restrict__ fd,
    int n, int nch, int gwid, int nwaves) {
    constexpr int C  = COLS2 / 2;
    constexpr int NC = COLS2 / 64;

    const int lane = threadIdx.x & 63;
    const int m = lane & 15, quad = lane >> 4;
    const int cs = gwid % NC;
    const int cstride = nwaves / NC;

    float biasv[4];
#pragma unroll
    for (int ct = 0; ct < 4; ++ct) {
        int col = cs * 64 + ct * 16 + m;
        biasv[ct] = (col < C) ? bs[col] : bd[col - C];
    }

    for (int chunk = gwid / NC; chunk < nch; chunk += cstride) {
        const size_t r0 = (size_t)chunk * 64;

        f32x4 acc[4][4];
#pragma unroll
        for (int rt = 0; rt < 4; ++rt)
#pragma unroll
            for (int ct = 0; ct < 4; ++ct) acc[rt][ct] = (f32x4){0.f, 0.f, 0.f, 0.f};

#pragma unroll
        for (int ks = 0; ks < 4; ++ks) {
            const int ko = ks * 32 + quad * 8;
            bf16x8 a[4], b[4];
#pragma unroll
            for (int rt = 0; rt < 4; ++rt)
                a[rt] = *(const bf16x8*)(xb + (r0 + rt * 16 + m) * 128 + ko);
#pragma unroll
            for (int ct = 0; ct < 4; ++ct)
                b[ct] = *(const bf16x8*)(wt + (size_t)(cs * 64 + ct * 16 + m) * 128 + ko);
#pragma unroll
            for (int rt = 0; rt < 4; ++rt)
#pragma unroll
                for (int ct = 0; ct < 4; ++ct)
                    acc[rt][ct] = __builtin_amdgcn_mfma_f32_16x16x32_bf16(a[rt], b[ct], acc[rt][ct], 0, 0, 0);
        }

        const int odd = m & 1;
#pragma unroll
        for (int ct = 0; ct < 4; ++ct) {
            int colE = cs * 64 + ct * 16 + (m & ~1);
            unsigned short* ptr = (colE < C) ? fs : fd;
            int cc = (colE < C) ? colE : colE - C;
#pragma unroll
            for (int rt = 0; rt < 4; ++rt) {
                float v0 = acc[rt][ct][0] + biasv[ct];
                float v1 = acc[rt][ct][1] + biasv[ct];
                float v2 = acc[rt][ct][2] + biasv[ct];
                float v3 = acc[rt][ct][3] + biasv[ct];
                float s0 = dpp_swap1(v0), s1 = dpp_swap1(v1);
                float s2 = dpp_swap1(v2), s3 = dpp_swap1(v3);
                float aLo = odd ? s2 : v0, aHi = odd ? v2 : s0;
                float bLo = odd ? s3 : v1, bHi = odd ? v3 : s1;
                int rowA = (int)r0 + rt * 16 + quad * 4 + (odd ? 2 : 0);
                unsigned pa = (bf_rn(aHi) << 16) | bf_rn(aLo);
                unsigned pb = (bf_rn(bHi) << 16) | bf_rn(bLo);
                if (rowA < n)     *(unsigned*)(ptr + (size_t)rowA * C + cc)       = pa;
                if (rowA + 1 < n) *(unsigned*)(ptr + ((size_t)rowA + 1) * C + cc) = pb;
            }
        }
    }
}

template <int COLS2>
__global__ __launch_bounds__(256) void gemm_dual2(
    const unsigned short* __restrict__ xb, const unsigned short* __restrict__ wt,
    const float* __restrict__ bs, const float* __restrict__ bd,
    unsigned short* __restrict__ fs, unsigned short* __restrict__ fd,
    int n, int nch) {
    gemm_core<COLS2>(xb, wt, bs, bd, fs, fd, n, nch,
                     blockIdx.x * 4 + (threadIdx.x >> 6), gridDim.x * 4);
}

// ---------------------------------------------------------------------------
// Fused: bin_count (blocks [0,nchunks)) + layer-0 GEMM (remaining blocks).
// Both depend only on prep.
// ---------------------------------------------------------------------------

__global__ __launch_bounds__(256) void count_gemm0(
    const int* __restrict__ dst, int* __restrict__ binCnt, int e, int nchunks,
    const unsigned short* __restrict__ xb, const unsigned short* __restrict__ wt,
    const float* __restrict__ bs, const float* __restrict__ bd,
    unsigned short* __restrict__ fs, unsigned short* __restrict__ fd,
    int n, int nch) {
    if ((int)blockIdx.x < nchunks) {
        __shared__ int hist[NBIN];
        for (int t = threadIdx.x; t < NBIN; t += 256) hist[t] = 0;
        __syncthreads();
        int base = blockIdx.x * CHUNK;
        int cnt = min(CHUNK, e - base);
        for (int j = threadIdx.x; j < cnt; j += 256)
            atomicAdd(&hist[dst[base + j] >> BINSH], 1);
        __syncthreads();
        for (int t = threadIdx.x; t < NBIN; t += 256)
            if (hist[t]) atomicAdd(&binCnt[t], hist[t]);
    } else {
        int bid = blockIdx.x - nchunks;
        gemm_core<256>(xb, wt, bs, bd, fs, fd, n, nch,
                       bid * 4 + (threadIdx.x >> 6), (gridDim.x - nchunks) * 4);
    }
}

// ---------------------------------------------------------------------------
// bin_scatter: local scan of binCnt (no bin_scan kernel), two-pass pack.
// ---------------------------------------------------------------------------

__global__ __launch_bounds__(256) void bin_scatter(
    const int* __restrict__ src, const int* __restrict__ dst,
    const int* __restrict__ binCnt, int* __restrict__ binOff,
    unsigned* __restrict__ ebin, int e) {
    __shared__ int hist[256];
    __shared__ int seg[256];
    __shared__ int bbase[256];
    __shared__ int gbase[NBIN];
    __shared__ unsigned pack[CHUNK];
    for (int t = threadIdx.x; t < 256; t += 256) hist[t] = 0;
    // local exclusive scan of global binCnt -> bbase (196 vals, one wave)
    if (threadIdx.x < 64) {
        int l = threadIdx.x;
        int s = 0, loc[4];
#pragma unroll
        for (int k = 0; k < 4; ++k) {
            int idx = l * 4 + k;
            int v = (idx < NBIN) ? binCnt[idx] : 0;
            loc[k] = s; s += v;
        }
        int incl = s;
        for (int off = 1; off < 64; off <<= 1) {
            int tt = __shfl_up(incl, off);
            if (l >= off) incl += tt;
        }
        int excl = incl - s;
#pragma unroll
        for (int k = 0; k < 4; ++k) bbase[l * 4 + k] = excl + loc[k];
    }
    __syncthreads();
    int base = blockIdx.x * CHUNK;
    int cnt = min(CHUNK, e - base);

    // pass 1: count per bin
    for (int j = threadIdx.x; j < cnt; j += 256)
        atomicAdd(&hist[dst[base + j] >> BINSH], 1);
    __syncthreads();
    // parallel exclusive scan of the local 256 buckets
    if (threadIdx.x < 64) {
        int l = threadIdx.x;
        int s = 0, loc[4];
#pragma unroll
        for (int k = 0; k < 4; ++k) { loc[k] = s; s += hist[l * 4 + k]; }
        int incl = s;
        for (int off = 1; off < 64; off <<= 1) {
            int tt = __shfl_up(incl, off);
            if (l >= off) incl += tt;
        }
        int excl = incl - s;
#pragma unroll
        for (int k = 0; k < 4; ++k) seg[l * 4 + k] = excl + loc[k];
    }
    __syncthreads();
    // allocate global range per non-empty bin (zero-based cursor + base)
    if (threadIdx.x < NBIN && hist[threadIdx.x])
        gbase[threadIdx.x] = bbase[threadIdx.x] + atomicAdd(&binOff[threadIdx.x], hist[threadIdx.x]);
    __syncthreads();
    for (int t = threadIdx.x; t < 256; t += 256) hist[t] = seg[t];
    __syncthreads();
    // pass 2: re-read (L2 hit) and pack into bin-sorted LDS
    for (int j = threadIdx.x; j < cnt; j += 256) {
        int d = dst[base + j], s = src[base + j];
        int b = d >> BINSH, dl = d & ((1 << BINSH) - 1);
        int pos = atomicAdd(&hist[b], 1);
        pack[pos] = ((unsigned)b << 24) | ((unsigned)dl << 16) | (unsigned)s;
    }
    __syncthreads();
    // coalesced-ish global write per bin run
    for (int j = threadIdx.x; j < cnt; j += 256) {
        unsigned wv = pack[j];
        int b = wv >> 24;
        ebin[gbase[b] + (j - seg[b])] = wv;
    }
}

// ---------------------------------------------------------------------------
// csr_build: local scan of binCnt for e0/e1; per-node counting sort.
// ---------------------------------------------------------------------------

__global__ __launch_bounds__(256) void csr_build(
    const unsigned* __restrict__ ebin, const int* __restrict__ binCnt,
    int* __restrict__ rowp, int* __restrict__ csrc, int n) {
    __shared__ int hist[256];
    __shared__ int seg[256];
    __shared__ int bbase[257];
    __shared__ unsigned stage[K4CAP];
    int b = blockIdx.x;
    // local exclusive scan of binCnt (196 vals); bbase[NBIN] = E total
    if (threadIdx.x < 64) {
        int l = threadIdx.x;
        int s = 0, loc[4];
#pragma unroll
        for (int k = 0; k < 4; ++k) {
            int idx = l * 4 + k;
            int v = (idx < NBIN) ? binCnt[idx] : 0;
            loc[k] = s; s += v;
        }
        int incl = s;
        for (int off = 1; off < 64; off <<= 1) {
            int tt = __shfl_up(incl, off);
            if (l >= off) incl += tt;
        }
        int excl = incl - s;
#pragma unroll
        for (int k = 0; k < 4; ++k) bbase[l * 4 + k] = excl + loc[k];
        if (l == 63) bbase[256] = incl;
    }
    for (int t = threadIdx.x; t < 256; t += 256) hist[t] = 0;
    __syncthreads();
    int e0 = bbase[b], e1 = bbase[b + 1];
    int n0 = b << BINSH;
    int nn = min(256, n - n0);
    if (b == NBIN - 1 && threadIdx.x == 0) rowp[n] = bbase[NBIN];
    for (int i = e0 + threadIdx.x; i < e1; i += 256) {
        unsigned wv = ebin[i];
        atomicAdd(&hist[(wv >> 16) & 255], 1);
        int off = i - e0;
        if (off < K4CAP) stage[off] = wv;
    }
    __syncthreads();
    if (threadIdx.x < 64) {
        int l = threadIdx.x;
        int s = 0, loc[4];
#pragma unroll
        for (int k = 0; k < 4; ++k) { loc[k] = s; s += hist[l * 4 + k]; }
        int incl = s;
        for (int off = 1; off < 64; off <<= 1) {
            int tt = __shfl_up(incl, off);
            if (l >= off) incl += tt;
        }
        int excl = incl - s;
#pragma unroll
        for (int k = 0; k < 4; ++k) seg[l * 4 + k] = excl + loc[k];
    }
    __syncthreads();
    for (int t = threadIdx.x; t < nn; t += 256) rowp[n0 + t] = e0 + seg[t];
    for (int t = threadIdx.x; t < 256; t += 256) hist[t] = seg[t];
    __syncthreads();
    for (int i = e0 + threadIdx.x; i < e1; i += 256) {
        int off = i - e0;
        unsigned wv = (off < K4CAP) ? stage[off] : ebin[i];
        int dl = (wv >> 16) & 255;
        int pos = e0 + atomicAdd(&hist[dl], 1);
        csrc[pos] = (int)(wv & 0xFFFFu);
    }
}

// ---------------------------------------------------------------------------
// GATv2 aggregation (baseline, measured-best form).
// conv128: 2 edges/wave (32 lanes = 4 feats/lane each); 4 edges in flight.
// conv32: 8 edges/wave (8 lanes = 4 feats/lane each). 8-lane DPP reduction.
// ---------------------------------------------------------------------------

// per-edge math: 4 feats/lane, 8-lane head groups. mval masks ex (1.0 folds).
#define EDGE_BODY(u, mval)                                          \
    do {                                                            \
        float x0 = bf_lo((u).x), x1 = bf_hi((u).x);                 \
        float x2 = bf_lo((u).y), x3 = bf_hi((u).y);                 \
        float t0 = x0 + fd0, t1 = x1 + fd1;                         \
        float t2 = x2 + fd2, t3 = x3 + fd3;                         \
        float p = a060 * t0;                                        \
        p = fmaf(a040, fabsf(t0), p);                               \
        p = fmaf(a061, t1, p); p = fmaf(a041, fabsf(t1), p);        \
        p = fmaf(a062, t2, p); p = fmaf(a042, fabsf(t2), p);        \
        p = fmaf(a063, t3, p); p = fmaf(a043, fabsf(t3), p);        \
        p = sum8(p);                                                \
        float ex = fast_exp2(p) * (mval);                           \
        denom += ex;                                                \
        acc0 = fmaf(ex, x0, acc0); acc1 = fmaf(ex, x1, acc1);       \
        acc2 = fmaf(ex, x2, acc2); acc3 = fmaf(ex, x3, acc3);       \
    } while (0)

__global__ __launch_bounds__(256) void conv128(
    const unsigned short* __restrict__ fs, const unsigned short* __restrict__ fd,
    const float* __restrict__ attn, const int* __restrict__ rowp,
    const int* __restrict__ csrc, unsigned short* __restrict__ out, int n) {
    const int nwaves = gridDim.x * 4;
    const int wid0 = blockIdx.x * 4 + (threadIdx.x >> 6);
    const int lane = threadIdx.x & 63;
    const int half = lane >> 5;     // which edge of the pair
    const int q = lane & 31;        // 4-feat chunk [0,32); head = q>>3

    float4 av = *(const float4*)(attn + q * 4);
    const float a060 = av.x * 0.6f * LOG2E, a040 = av.x * 0.4f * LOG2E;
    const float a061 = av.y * 0.6f * LOG2E, a041 = av.y * 0.4f * LOG2E;
    const float a062 = av.z * 0.6f * LOG2E, a042 = av.z * 0.4f * LOG2E;
    const float a063 = av.w * 0.6f * LOG2E, a043 = av.w * 0.4f * LOG2E;

    for (int wid = wid0; wid < n; wid += nwaves) {
        uint2 ud = *(const uint2*)(fd + (size_t)wid * 128 + q * 4);
        float fd0 = bf_lo(ud.x), fd1 = bf_hi(ud.x);
        float fd2 = bf_lo(ud.y), fd3 = bf_hi(ud.y);
        int rs = rowp[wid], re = rowp[wid + 1];
        float acc0 = 0.f, acc1 = 0.f, acc2 = 0.f, acc3 = 0.f, denom = 0.f;

        int i = rs;
        // two pairs (4 edges) in flight
        for (; i + 3 < re; i += 4) {
            int sA = csrc[i + half];
            int sB = csrc[i + 2 + half];
            uint2 uA = *(const uint2*)(fs + ((size_t)sA << 7) + q * 4);
            uint2 uB = *(const uint2*)(fs + ((size_t)sB << 7) + q * 4);
            EDGE_BODY(uA, 1.0f);
            EDGE_BODY(uB, 1.0f);
        }
        for (; i + 1 < re; i += 2) {
            int s = csrc[i + half];
            uint2 u = *(const uint2*)(fs + ((size_t)s << 7) + q * 4);
            EDGE_BODY(u, 1.0f);
        }
        if (i < re) {  // odd tail: both halves load same edge, half 1 masked
            int s = csrc[i];
            uint2 u = *(const uint2*)(fs + ((size_t)s << 7) + q * 4);
            float mval = half ? 0.f : 1.f;
            EDGE_BODY(u, mval);
        }
        // combine the two halves
        acc0 += __shfl_xor(acc0, 32); acc1 += __shfl_xor(acc1, 32);
        acc2 += __shfl_xor(acc2, 32); acc3 += __shfl_xor(acc3, 32);
        denom += __shfl_xor(denom, 32);
        float inv = (re > rs) ? 1.f / denom : 0.f;
        float r0 = fmaxf(acc0 * inv, 0.f), r1 = fmaxf(acc1 * inv, 0.f);
        float r2 = fmaxf(acc2 * inv, 0.f), r3 = fmaxf(acc3 * inv, 0.f);
        if (half == 0) {
            uint2 o;
            o.x = (bf_rn(r1) << 16) | bf_rn(r0);
            o.y = (bf_rn(r3) << 16) | bf_rn(r2);
            ((uint2*)(out + (size_t)wid * 128))[q] = o;
        }
    }
}

// Layer 2: 1 head x 32 feats; 8 edges/wave, 8 lanes (4 feats each) per edge.
__global__ __launch_bounds__(256) void conv32(
    const unsigned short* __restrict__ fs, const unsigned short* __restrict__ fd,
    const float* __restrict__ attn, const int* __restrict__ rowp,
    const int* __restrict__ csrc, float* __restrict__ out, int n) {
    const int nwaves = gridDim.x * 4;
    const int wid0 = blockIdx.x * 4 + (threadIdx.x >> 6);
    const int lane = threadIdx.x & 63;
    const int g = lane >> 3;    // edge slot [0,8)
    const int c = lane & 7;     // 4-feat chunk [0,8)

    float4 av = *(const float4*)(attn + c * 4);
    const float a060 = av.x * 0.6f * LOG2E, a040 = av.x * 0.4f * LOG2E;
    const float a061 = av.y * 0.6f * LOG2E, a041 = av.y * 0.4f * LOG2E;
    const float a062 = av.z * 0.6f * LOG2E, a042 = av.z * 0.4f * LOG2E;
    const float a063 = av.w * 0.6f * LOG2E, a043 = av.w * 0.4f * LOG2E;

    for (int wid = wid0; wid < n; wid += nwaves) {
        uint2 ud = *(const uint2*)(fd + (size_t)wid * 32 + c * 4);
        float fd0 = bf_lo(ud.x), fd1 = bf_hi(ud.x);
        float fd2 = bf_lo(ud.y), fd3 = bf_hi(ud.y);
        int rs = rowp[wid], re = rowp[wid + 1];
        float acc0 = 0.f, acc1 = 0.f, acc2 = 0.f, acc3 = 0.f, denom = 0.f;

        int i = rs;
        for (; i + 7 < re; i += 8) {
            int s = csrc[i + g];
            uint2 u = *(const uint2*)(fs + ((size_t)s << 5) + c * 4);
            EDGE_BODY(u, 1.0f);
        }
        if (i < re) {  // masked tail group
            int idx = i + g;
            int s = csrc[min(idx, re - 1)];
            uint2 u = *(const uint2*)(fs + ((size_t)s << 5) + c * 4);
            float mval = (idx < re) ? 1.f : 0.f;
            EDGE_BODY(u, mval);
        }
        // combine the 8 edge slots: rot8-within-16 (DPP), then xor 16, 32
        acc0 = dpp_radd<0x128>(acc0); acc1 = dpp_radd<0x128>(acc1);
        acc2 = dpp_radd<0x128>(acc2); acc3 = dpp_radd<0x128>(acc3);
        denom = dpp_radd<0x128>(denom);
        acc0 += __shfl_xor(acc0, 16); acc1 += __shfl_xor(acc1, 16);
        acc2 += __shfl_xor(acc2, 16); acc3 += __shfl_xor(acc3, 16);
        denom += __shfl_xor(denom, 16);
        acc0 += __shfl_xor(acc0, 32); acc1 += __shfl_xor(acc1, 32);
        acc2 += __shfl_xor(acc2, 32); acc3 += __shfl_xor(acc3, 32);
        denom += __shfl_xor(denom, 32);
        float inv = (re > rs) ? 1.f / denom : 0.f;
        if (lane < 8) {
            float4 o;
            o.x = acc0 * inv; o.y = acc1 * inv;
            o.z = acc2 * inv; o.w = acc3 * inv;
            *(float4*)(out + (size_t)wid * 32 + c * 4) = o;
        }
    }
}

// ---------------------------------------------------------------------------

extern "C" void kernel_launch(void* const* d_in, const int* in_sizes, int n_in,
                              void* d_out, int out_size, void* d_ws, size_t ws_size,
                              hipStream_t stream) {
    const float* feats = (const float*)d_in[0];
    const int*   src   = (const int*)d_in[1];
    const int*   dst   = (const int*)d_in[2];
    const float* Ws0 = (const float*)d_in[3],  *bs0 = (const float*)d_in[4];
    const float* Wd0 = (const float*)d_in[5],  *bd0 = (const float*)d_in[6];
    const float* a0  = (const float*)d_in[7];
    const float* Ws1 = (const float*)d_in[8],  *bs1 = (const float*)d_in[9];
    const float* Wd1 = (const float*)d_in[10], *bd1 = (const float*)d_in[11];
    const float* a1  = (const float*)d_in[12];
    const float* Ws2 = (const float*)d_in[13], *bs2 = (const float*)d_in[14];
    const float* Wd2 = (const float*)d_in[15], *bd2 = (const float*)d_in[16];
    const float* a2  = (const float*)d_in[17];

    const int N = in_sizes[0] / 128;  // 50000
    const int E = in_sizes[1];        // 800000
    const int nch = (N + 63) / 64;
    const int NPAD = nch * 64;

    char* ws = (char*)d_ws;
    const size_t featB = (size_t)NPAD * 128 * 2;
    unsigned short* xb  = (unsigned short*)(ws);
    unsigned short* hb  = (unsigned short*)(ws + featB);
    unsigned short* fsb = (unsigned short*)(ws + 2 * featB);
    unsigned short* fdb = (unsigned short*)(ws + 3 * featB);
    char* p = ws + 4 * featB;
    unsigned short* wt0 = (unsigned short*)p; p += 256 * 128 * 2;
    unsigned short* wt1 = (unsigned short*)p; p += 256 * 128 * 2;
    unsigned short* wt2 = (unsigned short*)p; p += 64 * 128 * 2;
    int* rowp    = (int*)p;      p += ((size_t)(N + 1) * 4 + 255) / 256 * 256;
    int* binCnt  = (int*)p;      p += (NBIN * 4 + 255) / 256 * 256;
    int* binOff  = (int*)p;      p += (NBIN * 4 + 255) / 256 * 256;
    unsigned* ebin = (unsigned*)p; p += (size_t)E * 4;
    int* csrc    = (int*)p;

    const int nchunks = (E + CHUNK - 1) / CHUNK;
    const int n4 = N * 128 / 4;

    const int g256 = nch;
    const int g64  = (nch + 3) / 4;
    const int convGrid = 2048;  // 8192 persistent waves

    // ---- K1: prep (feat convert + weight transpose + counter zero) ----
    prep<<<(n4 + 73728 + 255) / 256, 256, 0, stream>>>(
        feats, xb, n4, Ws0, Wd0, Ws1, Wd1, Ws2, Wd2, wt0, wt1, wt2, binCnt, binOff);

    // ---- K2: fused bin_count + layer-0 GEMM (independent work overlapped) ----
    count_gemm0<<<nchunks + g256, 256, 0, stream>>>(
        dst, binCnt, E, nchunks, xb, wt0, bs0, bd0, fsb, fdb, N, nch);

    // ---- K3/K4: CSR build (scan recomputed in-block; no bin_scan kernel) ----
    bin_scatter<<<nchunks, 256, 0, stream>>>(src, dst, binCnt, binOff, ebin, E);
    csr_build<<<NBIN, 256, 0, stream>>>(ebin, binCnt, rowp, csrc, N);

    // ---- layer 0 aggregation ----
    conv128<<<convGrid, 256, 0, stream>>>(fsb, fdb, a0, rowp, csrc, hb, N);
    // ---- layer 1 ----
    gemm_dual2<256><<<g256, 256, 0, stream>>>(hb, wt1, bs1, bd1, fsb, fdb, N, nch);
    conv128<<<convGrid, 256, 0, stream>>>(fsb, fdb, a1, rowp, csrc, hb, N);
    // ---- layer 2 ----
    gemm_dual2<64><<<g64, 256, 0, stream>>>(hb, wt2, bs2, bd2, fsb, fdb, N, nch);
    conv32<<<convGrid, 256, 0, stream>>>(fsb, fdb, a2, rowp, csrc, (float*)d_out, N);
}